// Round 5
// baseline (377.045 us; speedup 1.0000x reference)
//
#include <hip/hip_runtime.h>

// ---------------------------------------------------------------------------
// ImprovedLinkingPredictor round 17.
// Established: occupancy pinned ~2 blocks/CU for 40-63KB LDS; pool ~126KB;
// forcing VGPR spills; intra-block pairing kills the 2nd block. Best = r12
// (172us). Remaining structural cost: barriers from o-sliced GEMM1.
// r17: wave-autonomous pair_mlp. Each wave owns (i, 32 j's) for ALL o:
//  - GEMM1 B-frags built in registers from att (no scaledA staging, no B0).
//  - h1/h2/h3 + LN stats are wave-private (8KB LDS slice, chunk-XOR
//    swizzles, h2/h3 alias h1 after GEMM2). ZERO __syncthreads.
//  - 128-thr blocks (2 waves), grid (768,12). LDS 16KB/block -> up to 7
//    blocks/CU; VGPR ~120 (cap 170 via launch_bounds(128,3), no spill).
// Weight A-frags re-read per wave (~2GB L2 traffic, hidden at 34.5TB/s).
// pack_all / attn_mfma / gemm_attab unchanged.
// ---------------------------------------------------------------------------

typedef __attribute__((ext_vector_type(8))) __bf16 bf16x8;    // bf16 MFMA frag
typedef __attribute__((ext_vector_type(4))) float f32x4;      // 16x16 C/D
typedef __attribute__((ext_vector_type(8))) int i32x8;        // 32B fp8 frag

__device__ __forceinline__ float bf2f(unsigned short u) {
    return __uint_as_float(((unsigned int)u) << 16);
}
__device__ __forceinline__ unsigned short f2bf(float f) {
    union { __bf16 b; unsigned short u; } cv;
    cv.b = (__bf16)f;
    return cv.u;
}
__device__ __forceinline__ unsigned pk2(float lo, float hi) {
    return (unsigned)f2bf(lo) | ((unsigned)f2bf(hi) << 16);
}
__device__ __forceinline__ int pk4_fp8(float a, float b, float c, float d) {
    int w = __builtin_amdgcn_cvt_pk_fp8_f32(a, b, 0, false);
    w = __builtin_amdgcn_cvt_pk_fp8_f32(c, d, w, true);
    return w;
}
__device__ __forceinline__ unsigned char f2fp8(float v) {
    return (unsigned char)(__builtin_amdgcn_cvt_pk_fp8_f32(v, 0.f, 0, false) & 0xff);
}
__device__ __forceinline__ bf16x8 load8f_bf(const float* p) {
    float4 a = *reinterpret_cast<const float4*>(p);
    float4 b = *reinterpret_cast<const float4*>(p + 4);
    union { bf16x8 v; unsigned u[4]; } cv;
    cv.u[0] = pk2(a.x, a.y); cv.u[1] = pk2(a.z, a.w);
    cv.u[2] = pk2(b.x, b.y); cv.u[3] = pk2(b.z, b.w);
    return cv.v;
}
#define SC1 0x7F7F7F7F   // e8m0 scale = 1.0 in all bytes
#define MFMA_MX(a, b, c) __builtin_amdgcn_mfma_scale_f32_16x16x128_f8f6f4( \
        (a), (b), (c), 0, 0, 0, SC1, 0, SC1)

// ---------------- pack_all: packing + Wcomb + qkv GEMM ---------------------
__global__ __launch_bounds__(256) void pack_all(
    const float* __restrict__ features, const float* __restrict__ in_proj_w,
    const float* __restrict__ in_proj_b, const float* __restrict__ out_proj_w,
    const float* __restrict__ w1, const float* __restrict__ w2,
    const float* __restrict__ w3, const float* __restrict__ w4,
    const float* __restrict__ b1, const float* __restrict__ ln_g,
    const float* __restrict__ ln_b, const float* __restrict__ b2,
    const float* __restrict__ out_proj_b,
    unsigned short* __restrict__ qkvb, unsigned short* __restrict__ Vt,
    unsigned short* __restrict__ WcatB,
    unsigned char* __restrict__ w1c_mx, unsigned char* __restrict__ w1t_f8,
    unsigned char* __restrict__ w2g_mx, unsigned char* __restrict__ w3_mx,
    unsigned char* __restrict__ w4_f8,
    float* __restrict__ bias768, float* __restrict__ c1, float* __restrict__ c2)
{
    const int blk = blockIdx.x;
    if (blk < 716) {
        int t = blk * 256 + threadIdx.x;
        if (t < 65536) {                                // WcatB rows 0..255 = outW
            WcatB[t] = f2bf(out_proj_w[t]);
        } else if (t < 131072) {                        // w1c_mx: K=256 N=256, MX frag
            int u = t - 65536;
            int e = u & 31, lane = (u >> 5) & 63, f = u >> 11;
            int mt = f & 15, ks = f >> 4;
            int o = mt * 16 + (lane & 15);
            int k = ks * 128 + ((lane >> 4) & 3) * 32 + e;
            w1c_mx[u] = f2fp8(w1[o * 771 + 512 + k]);
        } else if (t < 139264) {                        // w1t_f8: spatial tail
            int u = t - 131072;
            int e = u & 7, lane = (u >> 3) & 63, f = u >> 9;
            int o = f * 16 + (lane & 15);
            int k = ((lane >> 4) & 3) * 8 + e;
            float v = (k < 3) ? w1[o * 771 + 768 + k] : 0.f;
            w1t_f8[u] = f2fp8(v);
        } else if (t < 172032) {                        // w2g_mx = w2*ln_g
            int u = t - 139264;
            int e = u & 31, lane = (u >> 5) & 63, f = u >> 11;
            int mt = f & 7, ks = f >> 3;
            int p = mt * 16 + (lane & 15);
            int k = ks * 128 + ((lane >> 4) & 3) * 32 + e;
            w2g_mx[u] = f2fp8(w2[p * 256 + k] * ln_g[k]);
        } else if (t < 180224) {                        // w3_mx: K=128 N=64
            int u = t - 172032;
            int e = u & 31, lane = (u >> 5) & 63, f = u >> 11;
            int o = f * 16 + (lane & 15);
            int k = ((lane >> 4) & 3) * 32 + e;
            w3_mx[u] = f2fp8(w3[o * 128 + k]);
        } else if (t < 182272) {                        // w4_f8 K=64 N=32 (16x16x32)
            int u = t - 180224;
            int e = u & 7, lane = (u >> 3) & 63, f = u >> 9;
            int l15 = lane & 15, quad = lane >> 4;
            int ct = f & 1, kc = f >> 1;
            int o = ct * 16 + l15, k = kc * 32 + quad * 8 + e;
            w4_f8[u] = f2fp8(w4[o * 64 + k]);
        } else if (t < 183040) {                        // bias768
            int n = t - 182272;
            if (n < 256) bias768[n] = out_proj_b[n];
            else {
                int m = n - 256;
                float s = 0.f;
                for (int d = 0; d < 256; d += 4) {
                    float4 ob = *reinterpret_cast<const float4*>(&out_proj_b[d]);
                    const float* wr = (m < 256) ? &w1[m * 771 + d]
                                                : &w1[(m - 256) * 771 + 256 + d];
                    float4 w = *reinterpret_cast<const float4*>(wr);
                    s += ob.x * w.x + ob.y * w.y + ob.z * w.z + ob.w * w.w;
                }
                bias768[n] = s + ((m < 256) ? b1[m] : 0.f);
            }
        } else if (t < 183168) {                        // c1/c2 LN-fold constants
            int p = t - 183040;
            float s2 = 0.f, s1 = 0.f;
            for (int k = 0; k < 256; k += 4) {
                float4 w = *reinterpret_cast<const float4*>(&w2[p * 256 + k]);
                float4 g = *reinterpret_cast<const float4*>(&ln_g[k]);
                float4 lb = *reinterpret_cast<const float4*>(&ln_b[k]);
                s2 += g.x * w.x + g.y * w.y + g.z * w.z + g.w * w.w;
                s1 += lb.x * w.x + lb.y * w.y + lb.z * w.z + lb.w * w.w;
            }
            c2[p] = s2;
            c1[p] = s1 + b2[p];
        }
    } else if (blk < 1228) {
        // ---- Wcomb[n][e] = sum_d wAB[n][d] * outW[d][e] -> WcatB rows 256+n
        const int n = blk - 716, e = threadIdx.x;
        const float* wrow = (n < 256) ? &w1[n * 771] : &w1[(n - 256) * 771 + 256];
        float acc = 0.f;
        for (int d = 0; d < 256; d += 4) {
            float4 w = *reinterpret_cast<const float4*>(&wrow[d]);
            acc += w.x * out_proj_w[(d + 0) * 256 + e];
            acc += w.y * out_proj_w[(d + 1) * 256 + e];
            acc += w.z * out_proj_w[(d + 2) * 256 + e];
            acc += w.w * out_proj_w[(d + 3) * 256 + e];
        }
        WcatB[(256 + n) * 256 + e] = f2bf(acc);
    } else {
        // ---- qkv GEMM (raw fp32 inputs, inline cvt): 144 blocks, 64x64 ----
        const int q = blk - 1228;
        const int bm = q % 12, bn = q / 12;
        const int wv = threadIdx.x >> 6, lane = threadIdx.x & 63;
        const int l15 = lane & 15, quad = lane >> 4;
        const int row0 = bm * 64 + wv * 16;
        const int col0 = bn * 64;
        f32x4 acc[4] = {};
        for (int kc = 0; kc < 8; ++kc) {
            bf16x8 a = load8f_bf(&features[(row0 + l15) * 256 + kc * 32 + quad * 8]);
#pragma unroll
            for (int ct = 0; ct < 4; ++ct) {
                bf16x8 b = load8f_bf(&in_proj_w[(col0 + ct * 16 + l15) * 256 + kc * 32 + quad * 8]);
                acc[ct] = __builtin_amdgcn_mfma_f32_16x16x32_bf16(a, b, acc[ct], 0, 0, 0);
            }
        }
#pragma unroll
        for (int ct = 0; ct < 4; ++ct)
#pragma unroll
            for (int r = 0; r < 4; ++r) {
                int row = row0 + quad * 4 + r, col = col0 + ct * 16 + l15;
                float v = acc[ct][r] + in_proj_b[col];
                if (col < 512) qkvb[row * 768 + col] = f2bf(v);
                else           Vt[(col - 512) * 768 + row] = f2bf(v);
            }
    }
}

// ---------------- fused [att | AB] GEMM ------------------------------------
__global__ __launch_bounds__(256) void gemm_attab(
    const unsigned short* __restrict__ A, const unsigned short* __restrict__ W,
    const float* __restrict__ bias, float* __restrict__ att,
    float* __restrict__ AB)
{
    const int wv = threadIdx.x >> 6, lane = threadIdx.x & 63;
    const int l15 = lane & 15, quad = lane >> 4;
    const int row0 = blockIdx.x * 64 + wv * 16;
    const int col0 = blockIdx.y * 64;
    f32x4 acc[4] = {};
    for (int kc = 0; kc < 8; ++kc) {
        bf16x8 a = *reinterpret_cast<const bf16x8*>(&A[(row0 + l15) * 256 + kc * 32 + quad * 8]);
#pragma unroll
        for (int ct = 0; ct < 4; ++ct) {
            bf16x8 b = *reinterpret_cast<const bf16x8*>(&W[(col0 + ct * 16 + l15) * 256 + kc * 32 + quad * 8]);
            acc[ct] = __builtin_amdgcn_mfma_f32_16x16x32_bf16(a, b, acc[ct], 0, 0, 0);
        }
    }
#pragma unroll
    for (int ct = 0; ct < 4; ++ct)
#pragma unroll
        for (int r = 0; r < 4; ++r) {
            int row = row0 + quad * 4 + r, col = col0 + ct * 16 + l15;
            float v = acc[ct][r] + bias[col];
            if (col < 256) att[row * 256 + col] = v;
            else           AB[row * 512 + (col - 256)] = v;
        }
}

// ---------------- fused MFMA attention: 32-row q-tiles, 1-pass softmax -----
#define SP 776

__global__ __launch_bounds__(256) void attn_mfma(
    const unsigned short* __restrict__ qkvb, const unsigned short* __restrict__ Vt,
    unsigned short* __restrict__ Obf)
{
    __shared__ __align__(16) unsigned short smS[32 * SP];   // 49.7 KB
    __shared__ float s_inv[32];
    const int h = blockIdx.x, q0 = blockIdx.y * 32, hb = h * 32;
    const int tid = threadIdx.x, wave = tid >> 6, lane = tid & 63;
    const int l15 = lane & 15, quad = lane >> 4;

    bf16x8 af[2];
#pragma unroll
    for (int mt = 0; mt < 2; ++mt)
        af[mt] = *reinterpret_cast<const bf16x8*>(&qkvb[(q0 + mt * 16 + l15) * 768 + hb + quad * 8]);
#pragma unroll
    for (int ct = 0; ct < 12; ++ct) {
        int n0 = wave * 192 + ct * 16;
        bf16x8 b = *reinterpret_cast<const bf16x8*>(&qkvb[(n0 + l15) * 768 + 256 + hb + quad * 8]);
#pragma unroll
        for (int mt = 0; mt < 2; ++mt) {
            f32x4 c = {};
            c = __builtin_amdgcn_mfma_f32_16x16x32_bf16(af[mt], b, c, 0, 0, 0);
#pragma unroll
            for (int r = 0; r < 4; ++r)
                smS[(mt * 16 + quad * 4 + r) * SP + n0 + l15] =
                    f2bf(c[r] * 0.17677669529663689f);
        }
    }
    __syncthreads();

    {   // 1-pass softmax: exp (unnormalized, bounded scores) + row sum
        const int row = tid >> 3, part = tid & 7;
        unsigned short* rp = &smS[row * SP + part * 96];
        float ls = 0.f;
#pragma unroll
        for (int c8 = 0; c8 < 12; ++c8) {
            uint4 v = *reinterpret_cast<const uint4*>(&rp[c8 * 8]);
            const unsigned short* pe = reinterpret_cast<const unsigned short*>(&v);
            unsigned short o8[8];
#pragma unroll
            for (int e = 0; e < 8; ++e) {
                float ev = __expf(bf2f(pe[e]));
                ls += ev;
                o8[e] = f2bf(ev);
            }
            *reinterpret_cast<uint4*>(&rp[c8 * 8]) = *reinterpret_cast<const uint4*>(o8);
        }
        ls += __shfl_xor(ls, 1, 64);
        ls += __shfl_xor(ls, 2, 64);
        ls += __shfl_xor(ls, 4, 64);
        if (part == 0) s_inv[row] = 1.0f / ls;
    }
    __syncthreads();

    const int row0 = (wave >> 1) * 16, cg = wave & 1;
    f32x4 accp = {};
    for (int kc = 0; kc < 24; ++kc) {
        bf16x8 a = *reinterpret_cast<const bf16x8*>(&smS[(row0 + l15) * SP + kc * 32 + quad * 8]);
        bf16x8 b = *reinterpret_cast<const bf16x8*>(&Vt[(hb + cg * 16 + l15) * 768 + kc * 32 + quad * 8]);
        accp = __builtin_amdgcn_mfma_f32_16x16x32_bf16(a, b, accp, 0, 0, 0);
    }
#pragma unroll
    for (int r = 0; r < 4; ++r) {
        int rloc = row0 + quad * 4 + r;
        Obf[(q0 + rloc) * 256 + hb + cg * 16 + l15] = f2bf(accp[r] * s_inv[rloc]);
    }
}

// ---------------- pair MLP v2: wave-autonomous, barrier-free ---------------
// Each wave owns (i, j-slice of 32) for ALL o. Per-wave LDS slice 8192 B:
//   h1 [32j][256k] fp8, chunk-XOR (ch^l15), bytes 0..8191
//   h2 [32j][128k] fp8, chunk-XOR (ch^(l15&7)), aliases h1 bytes 0..4095
//     (h1 fully consumed by G2's b2f reads before epi2 writes h2)
//   h3 [32j][stride 80] fp8, bytes 4096..6655 (h1 upper half, dead)
// LN stats: in-register partials + shfl over quads. No __syncthreads.
__global__ __launch_bounds__(128, 3) void pair_mlp(
    const float* __restrict__ att, const float* __restrict__ AB,
    const unsigned char* __restrict__ w1c_mx, const unsigned char* __restrict__ w1t_f8,
    const unsigned char* __restrict__ w2g_mx, const unsigned char* __restrict__ w3_mx,
    const unsigned char* __restrict__ w4_f8,
    const float* __restrict__ boxes,
    const float* __restrict__ c1, const float* __restrict__ c2,
    const float* __restrict__ b3, const float* __restrict__ b4,
    const float* __restrict__ w5, const float* __restrict__ b5,
    float* __restrict__ out)
{
    __shared__ __align__(16) unsigned char smPool[2][8192];
    const int tid = threadIdx.x, wave = tid >> 6, lane = tid & 63;
    const int l15 = lane & 15, quad = lane >> 4;
    const int i = blockIdx.x;
    const int j0w = blockIdx.y * 64 + wave * 32;

    unsigned char* const h1 = smPool[wave];
    unsigned char* const h2 = smPool[wave];          // aliases h1 (post-G2)
    unsigned char* const h3 = smPool[wave] + 4096;   // aliases h1 upper half

    // ---- build GEMM1 B-fragments in registers (fi*fj products) ----
    i32x8 bf[2][2];
    long long tf[2];
#pragma unroll
    for (int ks = 0; ks < 2; ++ks) {
        const int bk = ks * 128 + quad * 32;
        float4 fi[8];
#pragma unroll
        for (int c = 0; c < 8; ++c)
            fi[c] = *reinterpret_cast<const float4*>(&att[i * 256 + bk + c * 4]);
#pragma unroll
        for (int g = 0; g < 2; ++g) {
            const int j = j0w + g * 16 + l15;
            union { i32x8 v; int w[8]; } u;
#pragma unroll
            for (int c = 0; c < 8; ++c) {
                float4 fj = *reinterpret_cast<const float4*>(&att[j * 256 + bk + c * 4]);
                u.w[c] = pk4_fp8(fi[c].x * fj.x, fi[c].y * fj.y,
                                 fi[c].z * fj.z, fi[c].w * fj.w);
            }
            bf[g][ks] = u.v;
        }
    }
    {   // spatial tail frags (k 256..287: only k<3 nonzero -> quad 0)
        float bi0 = boxes[i * 4 + 0], bi1 = boxes[i * 4 + 1];
#pragma unroll
        for (int g = 0; g < 2; ++g) {
            int j = j0w + g * 16 + l15;
            float xd = fabsf(bi0 - boxes[j * 4 + 0]);
            float yd = bi1 - boxes[j * 4 + 1];
            int lo = pk4_fp8(xd, fabsf(yd), yd, 0.f);
            tf[g] = (quad == 0) ? (long long)(unsigned)lo : 0LL;
        }
    }

    // ---- GEMM1 + epi1 (o in 2 halves of 128); wave-local LN stats ----
    float vsA = 0.f, vsB = 0.f, vqA = 0.f, vqB = 0.f;
#pragma unroll
    for (int h = 0; h < 2; ++h) {
        f32x4 acc[8][2] = {};
#pragma unroll
        for (int ks = 0; ks < 2; ++ks)
#pragma unroll
            for (int m = 0; m < 8; ++m) {
                i32x8 a = *reinterpret_cast<const i32x8*>(
                    &w1c_mx[((ks * 16 + h * 8 + m) * 64 + lane) * 32]);
                acc[m][0] = MFMA_MX(a, bf[0][ks], acc[m][0]);
                acc[m][1] = MFMA_MX(a, bf[1][ks], acc[m][1]);
            }
#pragma unroll
        for (int m = 0; m < 8; ++m) {
            long long a = *reinterpret_cast<const long long*>(
                &w1t_f8[((h * 8 + m) * 64 + lane) * 8]);
            acc[m][0] = __builtin_amdgcn_mfma_f32_16x16x32_fp8_fp8(a, tf[0], acc[m][0], 0, 0, 0);
            acc[m][1] = __builtin_amdgcn_mfma_f32_16x16x32_fp8_fp8(a, tf[1], acc[m][1], 0, 0, 0);
        }
#pragma unroll
        for (int m = 0; m < 8; ++m) {
            const int o = h * 128 + m * 16 + quad * 4;
            float4 Ai = *reinterpret_cast<const float4*>(&AB[i * 512 + o]);
            float AiA[4] = {Ai.x, Ai.y, Ai.z, Ai.w};
#pragma unroll
            for (int g = 0; g < 2; ++g) {
                int j = j0w + g * 16 + l15;
                float4 Bj = *reinterpret_cast<const float4*>(&AB[j * 512 + 256 + o]);
                float BjA[4] = {Bj.x, Bj.y, Bj.z, Bj.w};
                float vv[4];
#pragma unroll
                for (int r = 0; r < 4; ++r) {
                    float v = fmaxf(acc[m][g][r] + AiA[r] + BjA[r], 0.f);
                    vv[r] = v;
                    if (g == 0) { vsA += v; vqA += v * v; }
                    else        { vsB += v; vqB += v * v; }
                }
                *reinterpret_cast<int*>(&h1[(g * 16 + l15) * 256 +
                    (((h * 8 + m) ^ l15) * 16) + quad * 4]) =
                    pk4_fp8(vv[0], vv[1], vv[2], vv[3]);
            }
        }
    }
    float mu[2], rs[2];
    {
        vsA += __shfl_xor(vsA, 16, 64); vsA += __shfl_xor(vsA, 32, 64);
        vqA += __shfl_xor(vqA, 16, 64); vqA += __shfl_xor(vqA, 32, 64);
        vsB += __shfl_xor(vsB, 16, 64); vsB += __shfl_xor(vsB, 32, 64);
        vqB += __shfl_xor(vqB, 16, 64); vqB += __shfl_xor(vqB, 32, 64);
        mu[0] = vsA * (1.0f / 256.0f);
        rs[0] = rsqrtf(vqA * (1.0f / 256.0f) - mu[0] * mu[0] + 1e-5f);
        mu[1] = vsB * (1.0f / 256.0f);
        rs[1] = rsqrtf(vqB * (1.0f / 256.0f) - mu[1] * mu[1] + 1e-5f);
    }

    // ---- GEMM2 (K=256) from wave-private h1 ----
    i32x8 b2f[2][2];
#pragma unroll
    for (int g = 0; g < 2; ++g)
#pragma unroll
        for (int ks = 0; ks < 2; ++ks) {
            const unsigned char* rp = &h1[(g * 16 + l15) * 256];
            const int cb = ks * 8 + quad * 2;
            union { i32x8 v; uint4 q[2]; } b;
            b.q[0] = *reinterpret_cast<const uint4*>(rp + ((cb    ) ^ l15) * 16);
            b.q[1] = *reinterpret_cast<const uint4*>(rp + ((cb + 1) ^ l15) * 16);
            b2f[g][ks] = b.v;
        }
    f32x4 acc2[8][2] = {};
#pragma unroll
    for (int ks = 0; ks < 2; ++ks)
#pragma unroll
        for (int m = 0; m < 8; ++m) {
            i32x8 a = *reinterpret_cast<const i32x8*>(
                &w2g_mx[((ks * 8 + m) * 64 + lane) * 32]);
            acc2[m][0] = MFMA_MX(a, b2f[0][ks], acc2[m][0]);
            acc2[m][1] = MFMA_MX(a, b2f[1][ks], acc2[m][1]);
        }
    // epi2: LN-folded affine + relu -> h2 (aliases h1; all h1 reads done)
#pragma unroll
    for (int m = 0; m < 8; ++m) {
        const int p = m * 16 + quad * 4;
        float4 C1v = *reinterpret_cast<const float4*>(&c1[p]);
        float4 C2v = *reinterpret_cast<const float4*>(&c2[p]);
        float C1A[4] = {C1v.x, C1v.y, C1v.z, C1v.w};
        float C2A[4] = {C2v.x, C2v.y, C2v.z, C2v.w};
#pragma unroll
        for (int g = 0; g < 2; ++g) {
            float vv[4];
#pragma unroll
            for (int r = 0; r < 4; ++r)
                vv[r] = fmaxf(rs[g] * (acc2[m][g][r] - mu[g] * C2A[r]) + C1A[r], 0.f);
            *reinterpret_cast<int*>(&h2[(g * 16 + l15) * 128 +
                ((m ^ (l15 & 7)) * 16) + quad * 4]) =
                pk4_fp8(vv[0], vv[1], vv[2], vv[3]);
        }
    }

    // ---- GEMM3 (K=128) ----
    i32x8 b3f[2];
#pragma unroll
    for (int g = 0; g < 2; ++g) {
        const unsigned char* rp = &h2[(g * 16 + l15) * 128];
        const int cb = quad * 2;
        union { i32x8 v; uint4 q[2]; } b;
        b.q[0] = *reinterpret_cast<const uint4*>(rp + ((cb    ) ^ (l15 & 7)) * 16);
        b.q[1] = *reinterpret_cast<const uint4*>(rp + ((cb + 1) ^ (l15 & 7)) * 16);
        b3f[g] = b.v;
    }
    f32x4 acc3[4][2] = {};
#pragma unroll
    for (int m = 0; m < 4; ++m) {
        i32x8 a = *reinterpret_cast<const i32x8*>(&w3_mx[(m * 64 + lane) * 32]);
        acc3[m][0] = MFMA_MX(a, b3f[0], acc3[m][0]);
        acc3[m][1] = MFMA_MX(a, b3f[1], acc3[m][1]);
    }
    // epi3 -> h3 (h1 upper half, dead since G2)
#pragma unroll
    for (int m = 0; m < 4; ++m) {
        const int qo = m * 16 + quad * 4;
        float4 B3 = *reinterpret_cast<const float4*>(&b3[qo]);
        float B3A[4] = {B3.x, B3.y, B3.z, B3.w};
#pragma unroll
        for (int g = 0; g < 2; ++g) {
            float vv[4];
#pragma unroll
            for (int r = 0; r < 4; ++r)
                vv[r] = fmaxf(acc3[m][g][r] + B3A[r], 0.f);
            *reinterpret_cast<int*>(&h3[(g * 16 + l15) * 80 + qo]) =
                pk4_fp8(vv[0], vv[1], vv[2], vv[3]);
        }
    }

    // ---- GEMM4 (K=64) + head ----
    f32x4 acc4[2][2] = {};
#pragma unroll
    for (int g = 0; g < 2; ++g)
#pragma unroll
        for (int kc = 0; kc < 2; ++kc) {
            long long b = *reinterpret_cast<const long long*>(
                &h3[(g * 16 + l15) * 80 + kc * 32 + quad * 8]);
#pragma unroll
            for (int t = 0; t < 2; ++t) {
                long long a = *reinterpret_cast<const long long*>(
                    &w4_f8[((kc * 2 + t) * 64 + lane) * 8]);
                acc4[t][g] = __builtin_amdgcn_mfma_f32_16x16x32_fp8_fp8(a, b, acc4[t][g], 0, 0, 0);
            }
        }
    float partA = 0.f, partB = 0.f;
#pragma unroll
    for (int t = 0; t < 2; ++t) {
        const int o4 = t * 16 + quad * 4;
        float4 B4 = *reinterpret_cast<const float4*>(&b4[o4]);
        float4 W5v = *reinterpret_cast<const float4*>(&w5[o4]);
        float B4A[4] = {B4.x, B4.y, B4.z, B4.w};
        float W5A[4] = {W5v.x, W5v.y, W5v.z, W5v.w};
#pragma unroll
        for (int r = 0; r < 4; ++r) {
            partA += fmaxf(acc4[t][0][r] + B4A[r], 0.f) * W5A[r];
            partB += fmaxf(acc4[t][1][r] + B4A[r], 0.f) * W5A[r];
        }
    }
    partA += __shfl_xor(partA, 16, 64); partA += __shfl_xor(partA, 32, 64);
    partB += __shfl_xor(partB, 16, 64); partB += __shfl_xor(partB, 32, 64);
    if (quad == 0) {
        int jA = j0w + l15;
        int jB = j0w + 16 + l15;
        out[i * 768 + jA] = (jA == i) ? -1.0e9f : partA + b5[0];
        out[i * 768 + jB] = (jB == i) ? -1.0e9f : partB + b5[0];
    }
}

// ---------------------------------------------------------------------------
extern "C" void kernel_launch(void* const* d_in, const int* in_sizes, int n_in,
                              void* d_out, int out_size, void* d_ws, size_t ws_size,
                              hipStream_t stream)
{
    const float* features   = (const float*)d_in[0];
    const float* boxes      = (const float*)d_in[1];
    const float* in_proj_w  = (const float*)d_in[2];
    const float* in_proj_b  = (const float*)d_in[3];
    const float* out_proj_w = (const float*)d_in[4];
    const float* out_proj_b = (const float*)d_in[5];
    const float* w1  = (const float*)d_in[6];
    const float* b1  = (const float*)d_in[7];
    const float* ln_g = (const float*)d_in[8];
    const float* ln_b = (const float*)d_in[9];
    const float* w2  = (const float*)d_in[10];
    const float* b2  = (const float*)d_in[11];
    const float* w3  = (const float*)d_in[12];
    const float* b3  = (const float*)d_in[13];
    const float* w4  = (const float*)d_in[14];
    const float* b4  = (const float*)d_in[15];
    const float* w5  = (const float*)d_in[16];
    const float* b5  = (const float*)d_in[17];
    float* out = (float*)d_out;

    // ---- workspace layout ----
    char* p = (char*)d_ws;
    unsigned short* qkvb  = (unsigned short*)p; p += 768 * 768 * 2;
    unsigned short* Vt    = (unsigned short*)p; p += 256 * 768 * 2;
    unsigned short* Obf   = (unsigned short*)p; p += 768 * 256 * 2;
    unsigned short* WcatB = (unsigned short*)p; p += 196608 * 2;   // [outW;Wcomb]
    float* att = (float*)p; p += 768 * 256 * 4;
    float* AB  = (float*)p; p += 768 * 512 * 4;
    unsigned char* w1c_mx = (unsigned char*)p; p += 65536;
    unsigned char* w1t_f8 = (unsigned char*)p; p += 8192;
    unsigned char* w2g_mx = (unsigned char*)p; p += 32768;
    unsigned char* w3_mx  = (unsigned char*)p; p += 8192;
    unsigned char* w4_f8  = (unsigned char*)p; p += 2048;
    float* bias768 = (float*)p; p += 768 * 4;
    float* c1v     = (float*)p; p += 128 * 4;
    float* c2v     = (float*)p; p += 128 * 4;

    // 1) pack + Wcomb + qkv GEMM
    pack_all<<<dim3(1372), dim3(256), 0, stream>>>(features, in_proj_w,
        in_proj_b, out_proj_w, w1, w2, w3, w4, b1, ln_g, ln_b, b2, out_proj_b,
        qkvb, Vt, WcatB, w1c_mx, w1t_f8, w2g_mx, w3_mx, w4_f8,
        bias768, c1v, c2v);
    // 2) attention
    attn_mfma<<<dim3(8, 24), dim3(256), 0, stream>>>(qkvb, Vt, Obf);
    // 3) [att | AB] = O @ WcatB^T + bias768
    gemm_attab<<<dim3(12, 12), dim3(256), 0, stream>>>(Obf, WcatB, bias768,
        att, AB);
    // 4) pair MLP v2: wave-autonomous, barrier-free
    pair_mlp<<<dim3(768, 12), dim3(128), 0, stream>>>(att, AB,
        w1c_mx, w1t_f8, w2g_mx, w3_mx, w4_f8, boxes, c1v, c2v,
        b3, b4, w5, b5, out);
}